// Round 9
// baseline (208.439 us; speedup 1.0000x reference)
//
#include <hip/hip_runtime.h>

#define D 128

typedef short s16x8 __attribute__((ext_vector_type(8)));
typedef ushort u16x8 __attribute__((ext_vector_type(8)));
typedef float f32x4 __attribute__((ext_vector_type(4)));

static __device__ __forceinline__ float bf2f(ushort h) {
    return __uint_as_float(((uint)h) << 16);
}
static __device__ __forceinline__ ushort f2bf(float f) {
    uint u = __float_as_uint(f);
    u += 0x7fffu + ((u >> 16) & 1u);   // RNE
    return (ushort)(u >> 16);
}

// ---------------- prep: x->bf16  +  degree count  +  W pack ----------------
// W B-fragment layout (mfma_f32_16x16x32_bf16): lane l, elem i holds
// W[ks*32 + (l>>4)*8 + i][nf*16 + (l&15)], packed at ((ks*8+nf)*64+lane)*8+i.
__global__ void prep_kernel(const float4* __restrict__ x4, ushort4* __restrict__ xh4, int n4,
                            const int* __restrict__ dst, int* __restrict__ cnt, int E,
                            const float* __restrict__ W1, const float* __restrict__ W2,
                            ushort* __restrict__ wp) {
    int tid = blockIdx.x * blockDim.x + threadIdx.x;
    int stride = gridDim.x * blockDim.x;
    for (int i = tid; i < n4; i += stride) {
        float4 v = x4[i];
        ushort4 h;
        h.x = f2bf(v.x); h.y = f2bf(v.y); h.z = f2bf(v.z); h.w = f2bf(v.w);
        xh4[i] = h;
    }
    for (int e = tid; e < E; e += stride) atomicAdd(&cnt[dst[e]], 1);
    if (tid < 4096) {
        int m = tid >> 11;
        int r = tid & 2047;
        int lane = r & 63;
        int nf = (r >> 6) & 7;
        int ks = r >> 9;
        const float* W = m ? W2 : W1;
        ushort* o = wp + m * 16384;
        int k0 = ks * 32 + ((lane >> 4) << 3);
        int c = nf * 16 + (lane & 15);
        #pragma unroll
        for (int i = 0; i < 8; ++i) o[r * 8 + i] = f2bf(W[(k0 + i) * D + c]);
    }
}

// ---------------- CSR alloc + fill ----------------
__global__ void alloc_kernel(const int* __restrict__ cnt, int* __restrict__ start,
                             int* __restrict__ cur, int* __restrict__ total, int n) {
    int i = blockIdx.x * blockDim.x + threadIdx.x;
    int lane = threadIdx.x & 63;
    int c = (i < n) ? cnt[i] : 0;
    int inc = c;
    #pragma unroll
    for (int s = 1; s < 64; s <<= 1) {
        int u = __shfl_up(inc, (unsigned)s);
        if (lane >= s) inc += u;
    }
    int base = 0;
    if (lane == 63) base = atomicAdd(total, inc);
    base = __shfl(base, 63);
    if (i < n) { int st = base + inc - c; start[i] = st; cur[i] = st; }
}

__global__ void fill_kernel(const int* __restrict__ src, const int* __restrict__ dst,
                            int* __restrict__ cur, int* __restrict__ bucket, int E) {
    int e = blockIdx.x * blockDim.x + threadIdx.x;
    if (e < E) {
        int p = atomicAdd(&cur[dst[e]], 1);
        bucket[p] = src[e];
    }
}

// ---------------- gather: z = xh + segment_sum(xh[src]) -> bf16 ----------------
// quarter-wave (16 lanes x 16B ushort8) per node; latency-bound, runs standalone
// at high occupancy (R4 taught: never fuse this with the MFMA kernels).
__global__ void gather_kernel(const u16x8* __restrict__ xh8,
                              const int* __restrict__ start, const int* __restrict__ cnt,
                              const int* __restrict__ bucket,
                              u16x8* __restrict__ z8, int n) {
    int node = blockIdx.x * 16 + (threadIdx.x >> 4);
    int lane = threadIdx.x & 15;
    if (node >= n) return;
    int e0 = start[node];
    int eend = e0 + cnt[node];
    float a[8];
    #pragma unroll
    for (int j = 0; j < 8; ++j) a[j] = 0.f;
    int e = e0;
    for (; e + 8 <= eend; e += 8) {
        int s0 = bucket[e],     s1 = bucket[e + 1], s2 = bucket[e + 2], s3 = bucket[e + 3];
        int s4 = bucket[e + 4], s5 = bucket[e + 5], s6 = bucket[e + 6], s7 = bucket[e + 7];
        u16x8 v0 = xh8[(size_t)s0 * 16 + lane];
        u16x8 v1 = xh8[(size_t)s1 * 16 + lane];
        u16x8 v2 = xh8[(size_t)s2 * 16 + lane];
        u16x8 v3 = xh8[(size_t)s3 * 16 + lane];
        u16x8 v4 = xh8[(size_t)s4 * 16 + lane];
        u16x8 v5 = xh8[(size_t)s5 * 16 + lane];
        u16x8 v6 = xh8[(size_t)s6 * 16 + lane];
        u16x8 v7 = xh8[(size_t)s7 * 16 + lane];
        #pragma unroll
        for (int j = 0; j < 8; ++j) {
            a[j] += bf2f(v0[j]) + bf2f(v1[j]) + bf2f(v2[j]) + bf2f(v3[j])
                  + bf2f(v4[j]) + bf2f(v5[j]) + bf2f(v6[j]) + bf2f(v7[j]);
        }
    }
    for (; e + 4 <= eend; e += 4) {
        int s0 = bucket[e], s1 = bucket[e + 1], s2 = bucket[e + 2], s3 = bucket[e + 3];
        u16x8 v0 = xh8[(size_t)s0 * 16 + lane];
        u16x8 v1 = xh8[(size_t)s1 * 16 + lane];
        u16x8 v2 = xh8[(size_t)s2 * 16 + lane];
        u16x8 v3 = xh8[(size_t)s3 * 16 + lane];
        #pragma unroll
        for (int j = 0; j < 8; ++j)
            a[j] += bf2f(v0[j]) + bf2f(v1[j]) + bf2f(v2[j]) + bf2f(v3[j]);
    }
    for (; e < eend; ++e) {
        int s = bucket[e];
        u16x8 v = xh8[(size_t)s * 16 + lane];
        #pragma unroll
        for (int j = 0; j < 8; ++j) a[j] += bf2f(v[j]);
    }
    u16x8 xv = xh8[(size_t)node * 16 + lane];
    u16x8 zo;
    #pragma unroll
    for (int j = 0; j < 8; ++j) zo[j] = f2bf(a[j] + bf2f(xv[j]));
    z8[(size_t)node * 16 + lane] = zo;
}

// ---------------- GEMM1: h1 = relu(z @ W1 + b1), bf16 out (W1 in LDS) ----------------
// Epilogue: acc -> per-wave LDS (XOR-swizzled) -> row-contiguous ushort8 stores
// (256B segments, full 128B lines; fixes the 32B-segment RMW of the scattered path).
__global__ __launch_bounds__(256, 3)
void gemm1_kernel(const ushort* __restrict__ Z, const ushort* __restrict__ Wp,
                  const float* __restrict__ bias, ushort* __restrict__ H1, int nTiles) {
    __shared__ ushort Ws[16384];        // 32 KB
    __shared__ ushort tbuf[4][2048];    // 4 KB per wave
    {
        const float4* g = (const float4*)Wp;
        float4* l = (float4*)Ws;
        for (int i = threadIdx.x; i < 2048; i += 256) l[i] = g[i];
    }
    __syncthreads();
    int wave = threadIdx.x >> 6, lane = threadIdx.x & 63;
    int rsel = lane & 15;
    int csel = lane >> 4;
    char* tb = (char*)tbuf[wave];
    for (int tile = blockIdx.x * 4 + wave; tile < nTiles; tile += gridDim.x * 4) {
        int row0 = tile * 16;
        const ushort* aP = Z + (size_t)(row0 + rsel) * D + csel * 8;
        f32x4 acc[8];
        #pragma unroll
        for (int nf = 0; nf < 8; ++nf) acc[nf] = (f32x4){0.f, 0.f, 0.f, 0.f};
        #pragma unroll
        for (int ks = 0; ks < 4; ++ks) {
            s16x8 a = *(const s16x8*)(aP + ks * 32);
            #pragma unroll
            for (int nf = 0; nf < 8; ++nf) {
                s16x8 b = *(const s16x8*)(&Ws[((ks * 8 + nf) * 64 + lane) * 8]);
                acc[nf] = __builtin_amdgcn_mfma_f32_16x16x32_bf16(a, b, acc[nf], 0, 0, 0);
            }
        }
        // acc -> LDS (bf16, swizzled); per-wave DS in-order, no barrier needed
        #pragma unroll
        for (int nf = 0; nf < 8; ++nf) {
            float bb = bias[nf * 16 + rsel];
            int col2 = (nf * 16 + rsel) * 2;
            #pragma unroll
            for (int r = 0; r < 4; ++r) {
                int rr = csel * 4 + r;
                float v = fmaxf(acc[nf][r] + bb, 0.f);
                *(ushort*)(tb + rr * 256 + (col2 ^ ((rr & 7) << 4))) = f2bf(v);
            }
        }
        // LDS -> global, row-contiguous
        #pragma unroll
        for (int i = 0; i < 4; ++i) {
            int row = i * 4 + csel;
            u16x8 v = *(const u16x8*)(tb + row * 256 + ((rsel * 16) ^ ((row & 7) << 4)));
            *(u16x8*)(H1 + (size_t)(row0 + row) * D + rsel * 8) = v;
        }
    }
}

// ---------------- GEMM2: out = h1 @ W2 + b2 (fp32) + fused BN stats ----------------
// Epilogue: two half-tile LDS transposes -> float4 stores (256B segments).
__global__ __launch_bounds__(256, 3)
void gemm2_kernel(const ushort* __restrict__ H1, const ushort* __restrict__ Wp,
                  const float* __restrict__ bias, float* __restrict__ out,
                  float* __restrict__ stats, int nTiles) {
    __shared__ ushort Ws[16384];      // 32 KB
    __shared__ float tbuf[4][1024];   // 4 KB per wave (half-tile fp32)
    __shared__ float sred[256];
    sred[threadIdx.x] = 0.f;
    {
        const float4* g = (const float4*)Wp;
        float4* l = (float4*)Ws;
        for (int i = threadIdx.x; i < 2048; i += 256) l[i] = g[i];
    }
    __syncthreads();
    int wave = threadIdx.x >> 6, lane = threadIdx.x & 63;
    int rsel = lane & 15;
    int csel = lane >> 4;
    char* tb = (char*)tbuf[wave];
    for (int tile = blockIdx.x * 4 + wave; tile < nTiles; tile += gridDim.x * 4) {
        int row0 = tile * 16;
        const ushort* aP = H1 + (size_t)(row0 + rsel) * D + csel * 8;
        f32x4 acc[8];
        #pragma unroll
        for (int nf = 0; nf < 8; ++nf) acc[nf] = (f32x4){0.f, 0.f, 0.f, 0.f};
        #pragma unroll
        for (int ks = 0; ks < 4; ++ks) {
            s16x8 a = *(const s16x8*)(aP + ks * 32);
            #pragma unroll
            for (int nf = 0; nf < 8; ++nf) {
                s16x8 b = *(const s16x8*)(&Ws[((ks * 8 + nf) * 64 + lane) * 8]);
                acc[nf] = __builtin_amdgcn_mfma_f32_16x16x32_bf16(a, b, acc[nf], 0, 0, 0);
            }
        }
        // two half-tiles: acc -> LDS fp32 (swizzled) -> contiguous float4 stores
        #pragma unroll
        for (int h = 0; h < 2; ++h) {
            #pragma unroll
            for (int nf = 0; nf < 4; ++nf) {
                int nfh = h * 4 + nf;
                int col = nfh * 16 + rsel;
                float bb = bias[col];
                int colb = (nf * 16 + rsel) * 4;
                float ps = 0.f, pq = 0.f;
                #pragma unroll
                for (int r = 0; r < 4; ++r) {
                    int rr = csel * 4 + r;
                    float v = acc[nfh][r] + bb;
                    *(float*)(tb + rr * 256 + (colb ^ ((rr & 7) << 4))) = v;
                    ps += v; pq += v * v;
                }
                ps += __shfl_xor(ps, 16); ps += __shfl_xor(ps, 32);
                pq += __shfl_xor(pq, 16); pq += __shfl_xor(pq, 32);
                if (csel == 0) {
                    atomicAdd(&sred[col], ps);
                    atomicAdd(&sred[128 + col], pq);
                }
            }
            #pragma unroll
            for (int i = 0; i < 4; ++i) {
                int row = i * 4 + csel;
                float4 v = *(const float4*)(tb + row * 256 + ((rsel * 16) ^ ((row & 7) << 4)));
                *(float4*)(out + (size_t)(row0 + row) * D + h * 64 + rsel * 4) = v;
            }
        }
    }
    __syncthreads();
    if (threadIdx.x < 256) atomicAdd(&stats[threadIdx.x], sred[threadIdx.x]);
}

// ---------------- BN normalize + residual ----------------
__global__ void bn_final(float4* __restrict__ out4, const float4* __restrict__ x4,
                         const float* __restrict__ stats, const float* __restrict__ gamma,
                         const float* __restrict__ beta, int n4, float invN) {
    int i = blockIdx.x * blockDim.x + threadIdx.x;
    if (i >= n4) return;
    int cc = i & 31;
    const float4* s4 = (const float4*)stats;
    float4 sum = s4[cc], sq = s4[32 + cc];
    float4 g = ((const float4*)gamma)[cc], b = ((const float4*)beta)[cc];
    float4 h = out4[i], xx = x4[i];
    float4 o;
    {
        float m = sum.x * invN, v = sq.x * invN - m * m, iv = rsqrtf(v + 1e-5f);
        o.x = (h.x - m) * iv * g.x + b.x + xx.x;
    }
    {
        float m = sum.y * invN, v = sq.y * invN - m * m, iv = rsqrtf(v + 1e-5f);
        o.y = (h.y - m) * iv * g.y + b.y + xx.y;
    }
    {
        float m = sum.z * invN, v = sq.z * invN - m * m, iv = rsqrtf(v + 1e-5f);
        o.z = (h.z - m) * iv * g.z + b.z + xx.z;
    }
    {
        float m = sum.w * invN, v = sq.w * invN - m * m, iv = rsqrtf(v + 1e-5f);
        o.w = (h.w - m) * iv * g.w + b.w + xx.w;
    }
    out4[i] = o;
}

extern "C" void kernel_launch(void* const* d_in, const int* in_sizes, int n_in,
                              void* d_out, int out_size, void* d_ws, size_t ws_size,
                              hipStream_t stream) {
    const float* x     = (const float*)d_in[0];
    const int*   ei    = (const int*)d_in[1];
    const float* W1    = (const float*)d_in[2];
    const float* b1    = (const float*)d_in[3];
    const float* W2    = (const float*)d_in[4];
    const float* b2    = (const float*)d_in[5];
    const float* gamma = (const float*)d_in[6];
    const float* beta  = (const float*)d_in[7];
    float* out = (float*)d_out;

    int N = in_sizes[0] / D;   // 50000
    int E = in_sizes[1] / 2;   // 600000
    const int* src = ei;
    const int* dst = ei + E;

    size_t NB = (size_t)N * D;
    ushort* xh   = (ushort*)d_ws;          // NB ushorts
    ushort* z    = xh + NB;                // NB ushorts
    ushort* h1   = z + NB;                 // NB ushorts
    ushort* wp   = h1 + NB;                // 2*16384
    float*  stats = (float*)(wp + 32768);  // 256 floats (16B aligned)
    int*    cnt  = (int*)(stats + 256);    // N
    int*    tot  = cnt + N;                // 1
    int*    startA = tot + 1;              // N
    int*    cur  = startA + N;             // N
    int*    bucket = cur + N;              // E

    hipMemsetAsync(stats, 0, (size_t)(256 + N + 1) * sizeof(int), stream);

    const int B = 256;
    int n4 = (int)(NB / 4);
    prep_kernel<<<2048, B, 0, stream>>>((const float4*)x, (ushort4*)xh, n4,
                                        dst, cnt, E, W1, W2, wp);
    alloc_kernel<<<(N + B - 1) / B, B, 0, stream>>>(cnt, startA, cur, tot, N);
    fill_kernel<<<(E + B - 1) / B, B, 0, stream>>>(src, dst, cur, bucket, E);
    gather_kernel<<<(N + 15) / 16, B, 0, stream>>>((const u16x8*)xh, startA, cnt, bucket,
                                                   (u16x8*)z, N);
    int nTiles = (N + 15) / 16;   // 3125
    gemm1_kernel<<<782, B, 0, stream>>>(z, wp, b1, h1, nTiles);
    gemm2_kernel<<<782, B, 0, stream>>>(h1, wp + 16384, b2, out, stats, nTiles);
    bn_final<<<(n4 + B - 1) / B, B, 0, stream>>>((float4*)out, (const float4*)x, stats,
                                                 gamma, beta, n4, 1.0f / (float)N);
}

// Round 10
// 174.200 us; speedup vs baseline: 1.1966x; 1.1966x over previous
//
#include <hip/hip_runtime.h>

#define D 128

typedef short s16x8 __attribute__((ext_vector_type(8)));
typedef ushort u16x8 __attribute__((ext_vector_type(8)));
typedef float f32x4 __attribute__((ext_vector_type(4)));

static __device__ __forceinline__ float bf2f(ushort h) {
    return __uint_as_float(((uint)h) << 16);
}
static __device__ __forceinline__ ushort f2bf(float f) {
    uint u = __float_as_uint(f);
    u += 0x7fffu + ((u >> 16) & 1u);   // RNE
    return (ushort)(u >> 16);
}

// ---------------- prep: x->bf16  +  degree count  +  W pack ----------------
// W B-fragment layout (mfma_f32_16x16x32_bf16): lane l, elem i holds
// W[ks*32 + (l>>4)*8 + i][nf*16 + (l&15)], packed at ((ks*8+nf)*64+lane)*8+i.
__global__ void prep_kernel(const float4* __restrict__ x4, ushort4* __restrict__ xh4, int n4,
                            const int* __restrict__ dst, int* __restrict__ cnt, int E,
                            const float* __restrict__ W1, const float* __restrict__ W2,
                            ushort* __restrict__ wp) {
    int tid = blockIdx.x * blockDim.x + threadIdx.x;
    int stride = gridDim.x * blockDim.x;
    for (int i = tid; i < n4; i += stride) {
        float4 v = x4[i];
        ushort4 h;
        h.x = f2bf(v.x); h.y = f2bf(v.y); h.z = f2bf(v.z); h.w = f2bf(v.w);
        xh4[i] = h;
    }
    for (int e = tid; e < E; e += stride) atomicAdd(&cnt[dst[e]], 1);
    if (tid < 4096) {
        int m = tid >> 11;
        int r = tid & 2047;
        int lane = r & 63;
        int nf = (r >> 6) & 7;
        int ks = r >> 9;
        const float* W = m ? W2 : W1;
        ushort* o = wp + m * 16384;
        int k0 = ks * 32 + ((lane >> 4) << 3);
        int c = nf * 16 + (lane & 15);
        #pragma unroll
        for (int i = 0; i < 8; ++i) o[r * 8 + i] = f2bf(W[(k0 + i) * D + c]);
    }
}

// ---------------- CSR alloc + fill ----------------
__global__ void alloc_kernel(const int* __restrict__ cnt, int* __restrict__ start,
                             int* __restrict__ cur, int* __restrict__ total, int n) {
    int i = blockIdx.x * blockDim.x + threadIdx.x;
    int lane = threadIdx.x & 63;
    int c = (i < n) ? cnt[i] : 0;
    int inc = c;
    #pragma unroll
    for (int s = 1; s < 64; s <<= 1) {
        int u = __shfl_up(inc, (unsigned)s);
        if (lane >= s) inc += u;
    }
    int base = 0;
    if (lane == 63) base = atomicAdd(total, inc);
    base = __shfl(base, 63);
    if (i < n) { int st = base + inc - c; start[i] = st; cur[i] = st; }
}

__global__ void fill_kernel(const int* __restrict__ src, const int* __restrict__ dst,
                            int* __restrict__ cur, int* __restrict__ bucket, int E) {
    int e = blockIdx.x * blockDim.x + threadIdx.x;
    if (e < E) {
        int p = atomicAdd(&cur[dst[e]], 1);
        bucket[p] = src[e];
    }
}

// ---------------- gather: z = xh + segment_sum(xh[src]) -> bf16 ----------------
// quarter-wave (16 lanes x 16B ushort8) per node; latency-bound, runs standalone
// at high occupancy (R4 taught: never fuse this with the MFMA kernels).
__global__ void gather_kernel(const u16x8* __restrict__ xh8,
                              const int* __restrict__ start, const int* __restrict__ cnt,
                              const int* __restrict__ bucket,
                              u16x8* __restrict__ z8, int n) {
    int node = blockIdx.x * 16 + (threadIdx.x >> 4);
    int lane = threadIdx.x & 15;
    if (node >= n) return;
    int e0 = start[node];
    int eend = e0 + cnt[node];
    float a[8];
    #pragma unroll
    for (int j = 0; j < 8; ++j) a[j] = 0.f;
    int e = e0;
    for (; e + 8 <= eend; e += 8) {
        int s0 = bucket[e],     s1 = bucket[e + 1], s2 = bucket[e + 2], s3 = bucket[e + 3];
        int s4 = bucket[e + 4], s5 = bucket[e + 5], s6 = bucket[e + 6], s7 = bucket[e + 7];
        u16x8 v0 = xh8[(size_t)s0 * 16 + lane];
        u16x8 v1 = xh8[(size_t)s1 * 16 + lane];
        u16x8 v2 = xh8[(size_t)s2 * 16 + lane];
        u16x8 v3 = xh8[(size_t)s3 * 16 + lane];
        u16x8 v4 = xh8[(size_t)s4 * 16 + lane];
        u16x8 v5 = xh8[(size_t)s5 * 16 + lane];
        u16x8 v6 = xh8[(size_t)s6 * 16 + lane];
        u16x8 v7 = xh8[(size_t)s7 * 16 + lane];
        #pragma unroll
        for (int j = 0; j < 8; ++j) {
            a[j] += bf2f(v0[j]) + bf2f(v1[j]) + bf2f(v2[j]) + bf2f(v3[j])
                  + bf2f(v4[j]) + bf2f(v5[j]) + bf2f(v6[j]) + bf2f(v7[j]);
        }
    }
    for (; e + 4 <= eend; e += 4) {
        int s0 = bucket[e], s1 = bucket[e + 1], s2 = bucket[e + 2], s3 = bucket[e + 3];
        u16x8 v0 = xh8[(size_t)s0 * 16 + lane];
        u16x8 v1 = xh8[(size_t)s1 * 16 + lane];
        u16x8 v2 = xh8[(size_t)s2 * 16 + lane];
        u16x8 v3 = xh8[(size_t)s3 * 16 + lane];
        #pragma unroll
        for (int j = 0; j < 8; ++j)
            a[j] += bf2f(v0[j]) + bf2f(v1[j]) + bf2f(v2[j]) + bf2f(v3[j]);
    }
    for (; e < eend; ++e) {
        int s = bucket[e];
        u16x8 v = xh8[(size_t)s * 16 + lane];
        #pragma unroll
        for (int j = 0; j < 8; ++j) a[j] += bf2f(v[j]);
    }
    u16x8 xv = xh8[(size_t)node * 16 + lane];
    u16x8 zo;
    #pragma unroll
    for (int j = 0; j < 8; ++j) zo[j] = f2bf(a[j] + bf2f(xv[j]));
    z8[(size_t)node * 16 + lane] = zo;
}

// ---------------- GEMM1: h1 = relu(z @ W1 + b1), bf16 out ----------------
// nf-split across waves: wave w owns output cols [w*32, w*32+32). Its W slice
// (8 s16x8 fragments = 32 VGPR) lives in REGISTERS, loaded once from L2-hot wp.
// No LDS, no barriers, no W-stage serialization -> 20 waves/CU residency.
__global__ __launch_bounds__(256, 5)
void gemm1_kernel(const ushort* __restrict__ Z, const ushort* __restrict__ wp,
                  const float* __restrict__ bias, ushort* __restrict__ H1, int nTiles) {
    int wave = threadIdx.x >> 6, lane = threadIdx.x & 63;
    int rsel = lane & 15;
    int csel = lane >> 4;
    int nf0 = wave * 2;
    s16x8 w0[4], w1[4];
    #pragma unroll
    for (int ks = 0; ks < 4; ++ks) {
        w0[ks] = *(const s16x8*)(wp + ((ks * 8 + nf0) * 64 + lane) * 8);
        w1[ks] = *(const s16x8*)(wp + ((ks * 8 + nf0 + 1) * 64 + lane) * 8);
    }
    float bb0 = bias[nf0 * 16 + rsel];
    float bb1 = bias[(nf0 + 1) * 16 + rsel];
    for (int tile = blockIdx.x; tile < nTiles; tile += gridDim.x) {
        int row0 = tile * 16;
        const ushort* aP = Z + (size_t)(row0 + rsel) * D + csel * 8;
        s16x8 a0 = *(const s16x8*)(aP);
        s16x8 a1 = *(const s16x8*)(aP + 32);
        s16x8 a2 = *(const s16x8*)(aP + 64);
        s16x8 a3 = *(const s16x8*)(aP + 96);
        f32x4 acc0 = (f32x4){0.f, 0.f, 0.f, 0.f};
        f32x4 acc1 = (f32x4){0.f, 0.f, 0.f, 0.f};
        acc0 = __builtin_amdgcn_mfma_f32_16x16x32_bf16(a0, w0[0], acc0, 0, 0, 0);
        acc1 = __builtin_amdgcn_mfma_f32_16x16x32_bf16(a0, w1[0], acc1, 0, 0, 0);
        acc0 = __builtin_amdgcn_mfma_f32_16x16x32_bf16(a1, w0[1], acc0, 0, 0, 0);
        acc1 = __builtin_amdgcn_mfma_f32_16x16x32_bf16(a1, w1[1], acc1, 0, 0, 0);
        acc0 = __builtin_amdgcn_mfma_f32_16x16x32_bf16(a2, w0[2], acc0, 0, 0, 0);
        acc1 = __builtin_amdgcn_mfma_f32_16x16x32_bf16(a2, w1[2], acc1, 0, 0, 0);
        acc0 = __builtin_amdgcn_mfma_f32_16x16x32_bf16(a3, w0[3], acc0, 0, 0, 0);
        acc1 = __builtin_amdgcn_mfma_f32_16x16x32_bf16(a3, w1[3], acc1, 0, 0, 0);
        int col0 = nf0 * 16 + rsel;
        int orow = row0 + csel * 4;
        #pragma unroll
        for (int r = 0; r < 4; ++r) {
            H1[(size_t)(orow + r) * D + col0]      = f2bf(fmaxf(acc0[r] + bb0, 0.f));
            H1[(size_t)(orow + r) * D + col0 + 16] = f2bf(fmaxf(acc1[r] + bb1, 0.f));
        }
    }
}

// ---------------- GEMM2: out = h1 @ W2 + b2 (fp32) + BN stats ----------------
// Same register-W nf-split; stats accumulated in registers across the wave's
// tiles, flushed once per wave at the end (no LDS, no barrier).
__global__ __launch_bounds__(256, 5)
void gemm2_kernel(const ushort* __restrict__ H1, const ushort* __restrict__ wp,
                  const float* __restrict__ bias, float* __restrict__ out,
                  float* __restrict__ stats, int nTiles) {
    int wave = threadIdx.x >> 6, lane = threadIdx.x & 63;
    int rsel = lane & 15;
    int csel = lane >> 4;
    int nf0 = wave * 2;
    s16x8 w0[4], w1[4];
    #pragma unroll
    for (int ks = 0; ks < 4; ++ks) {
        w0[ks] = *(const s16x8*)(wp + ((ks * 8 + nf0) * 64 + lane) * 8);
        w1[ks] = *(const s16x8*)(wp + ((ks * 8 + nf0 + 1) * 64 + lane) * 8);
    }
    float bb0 = bias[nf0 * 16 + rsel];
    float bb1 = bias[(nf0 + 1) * 16 + rsel];
    float s0 = 0.f, q0 = 0.f, s1 = 0.f, q1 = 0.f;
    for (int tile = blockIdx.x; tile < nTiles; tile += gridDim.x) {
        int row0 = tile * 16;
        const ushort* aP = H1 + (size_t)(row0 + rsel) * D + csel * 8;
        s16x8 a0 = *(const s16x8*)(aP);
        s16x8 a1 = *(const s16x8*)(aP + 32);
        s16x8 a2 = *(const s16x8*)(aP + 64);
        s16x8 a3 = *(const s16x8*)(aP + 96);
        f32x4 acc0 = (f32x4){0.f, 0.f, 0.f, 0.f};
        f32x4 acc1 = (f32x4){0.f, 0.f, 0.f, 0.f};
        acc0 = __builtin_amdgcn_mfma_f32_16x16x32_bf16(a0, w0[0], acc0, 0, 0, 0);
        acc1 = __builtin_amdgcn_mfma_f32_16x16x32_bf16(a0, w1[0], acc1, 0, 0, 0);
        acc0 = __builtin_amdgcn_mfma_f32_16x16x32_bf16(a1, w0[1], acc0, 0, 0, 0);
        acc1 = __builtin_amdgcn_mfma_f32_16x16x32_bf16(a1, w1[1], acc1, 0, 0, 0);
        acc0 = __builtin_amdgcn_mfma_f32_16x16x32_bf16(a2, w0[2], acc0, 0, 0, 0);
        acc1 = __builtin_amdgcn_mfma_f32_16x16x32_bf16(a2, w1[2], acc1, 0, 0, 0);
        acc0 = __builtin_amdgcn_mfma_f32_16x16x32_bf16(a3, w0[3], acc0, 0, 0, 0);
        acc1 = __builtin_amdgcn_mfma_f32_16x16x32_bf16(a3, w1[3], acc1, 0, 0, 0);
        int col0 = nf0 * 16 + rsel;
        int orow = row0 + csel * 4;
        #pragma unroll
        for (int r = 0; r < 4; ++r) {
            float v0 = acc0[r] + bb0;
            float v1 = acc1[r] + bb1;
            out[(size_t)(orow + r) * D + col0]      = v0;
            out[(size_t)(orow + r) * D + col0 + 16] = v1;
            s0 += v0; q0 += v0 * v0;
            s1 += v1; q1 += v1 * v1;
        }
    }
    // flush stats: reduce over the 4 csel groups, one atomic per col per wave
    s0 += __shfl_xor(s0, 16); s0 += __shfl_xor(s0, 32);
    q0 += __shfl_xor(q0, 16); q0 += __shfl_xor(q0, 32);
    s1 += __shfl_xor(s1, 16); s1 += __shfl_xor(s1, 32);
    q1 += __shfl_xor(q1, 16); q1 += __shfl_xor(q1, 32);
    if (csel == 0) {
        int col0 = nf0 * 16 + rsel;
        atomicAdd(&stats[col0], s0);
        atomicAdd(&stats[128 + col0], q0);
        atomicAdd(&stats[col0 + 16], s1);
        atomicAdd(&stats[128 + col0 + 16], q1);
    }
}

// ---------------- BN normalize + residual ----------------
__global__ void bn_final(float4* __restrict__ out4, const float4* __restrict__ x4,
                         const float* __restrict__ stats, const float* __restrict__ gamma,
                         const float* __restrict__ beta, int n4, float invN) {
    int i = blockIdx.x * blockDim.x + threadIdx.x;
    if (i >= n4) return;
    int cc = i & 31;
    const float4* s4 = (const float4*)stats;
    float4 sum = s4[cc], sq = s4[32 + cc];
    float4 g = ((const float4*)gamma)[cc], b = ((const float4*)beta)[cc];
    float4 h = out4[i], xx = x4[i];
    float4 o;
    {
        float m = sum.x * invN, v = sq.x * invN - m * m, iv = rsqrtf(v + 1e-5f);
        o.x = (h.x - m) * iv * g.x + b.x + xx.x;
    }
    {
        float m = sum.y * invN, v = sq.y * invN - m * m, iv = rsqrtf(v + 1e-5f);
        o.y = (h.y - m) * iv * g.y + b.y + xx.y;
    }
    {
        float m = sum.z * invN, v = sq.z * invN - m * m, iv = rsqrtf(v + 1e-5f);
        o.z = (h.z - m) * iv * g.z + b.z + xx.z;
    }
    {
        float m = sum.w * invN, v = sq.w * invN - m * m, iv = rsqrtf(v + 1e-5f);
        o.w = (h.w - m) * iv * g.w + b.w + xx.w;
    }
    out4[i] = o;
}

extern "C" void kernel_launch(void* const* d_in, const int* in_sizes, int n_in,
                              void* d_out, int out_size, void* d_ws, size_t ws_size,
                              hipStream_t stream) {
    const float* x     = (const float*)d_in[0];
    const int*   ei    = (const int*)d_in[1];
    const float* W1    = (const float*)d_in[2];
    const float* b1    = (const float*)d_in[3];
    const float* W2    = (const float*)d_in[4];
    const float* b2    = (const float*)d_in[5];
    const float* gamma = (const float*)d_in[6];
    const float* beta  = (const float*)d_in[7];
    float* out = (float*)d_out;

    int N = in_sizes[0] / D;   // 50000
    int E = in_sizes[1] / 2;   // 600000
    const int* src = ei;
    const int* dst = ei + E;

    size_t NB = (size_t)N * D;
    ushort* xh   = (ushort*)d_ws;          // NB ushorts
    ushort* z    = xh + NB;                // NB ushorts
    ushort* h1   = z + NB;                 // NB ushorts
    ushort* wp   = h1 + NB;                // 2*16384
    float*  stats = (float*)(wp + 32768);  // 256 floats (16B aligned)
    int*    cnt  = (int*)(stats + 256);    // N
    int*    tot  = cnt + N;                // 1
    int*    startA = tot + 1;              // N
    int*    cur  = startA + N;             // N
    int*    bucket = cur + N;              // E

    hipMemsetAsync(stats, 0, (size_t)(256 + N + 1) * sizeof(int), stream);

    const int B = 256;
    int n4 = (int)(NB / 4);
    prep_kernel<<<2048, B, 0, stream>>>((const float4*)x, (ushort4*)xh, n4,
                                        dst, cnt, E, W1, W2, wp);
    alloc_kernel<<<(N + B - 1) / B, B, 0, stream>>>(cnt, startA, cur, tot, N);
    fill_kernel<<<(E + B - 1) / B, B, 0, stream>>>(src, dst, cur, bucket, E);
    gather_kernel<<<(N + 15) / 16, B, 0, stream>>>((const u16x8*)xh, startA, cnt, bucket,
                                                   (u16x8*)z, N);
    int nTiles = (N + 15) / 16;   // 3125
    gemm1_kernel<<<1280, B, 0, stream>>>(z, wp, b1, h1, nTiles);
    gemm2_kernel<<<1280, B, 0, stream>>>(h1, wp + 16384, b2, out, stats, nTiles);
    bn_final<<<(n4 + B - 1) / B, B, 0, stream>>>((float4*)out, (const float4*)x, stats,
                                                 gamma, beta, n4, 1.0f / (float)N);
}

// Round 11
// 168.063 us; speedup vs baseline: 1.2402x; 1.0365x over previous
//
#include <hip/hip_runtime.h>

#define D 128

typedef short s16x8 __attribute__((ext_vector_type(8)));
typedef ushort u16x8 __attribute__((ext_vector_type(8)));
typedef float f32x4 __attribute__((ext_vector_type(4)));

static __device__ __forceinline__ float bf2f(ushort h) {
    return __uint_as_float(((uint)h) << 16);
}
static __device__ __forceinline__ ushort f2bf(float f) {
    uint u = __float_as_uint(f);
    u += 0x7fffu + ((u >> 16) & 1u);   // RNE
    return (ushort)(u >> 16);
}

// ---------------- prep: x->bf16  +  degree count  +  W pack ----------------
__global__ void prep_kernel(const float4* __restrict__ x4, ushort4* __restrict__ xh4, int n4,
                            const int* __restrict__ dst, int* __restrict__ cnt, int E,
                            const float* __restrict__ W1, const float* __restrict__ W2,
                            ushort* __restrict__ wp) {
    int tid = blockIdx.x * blockDim.x + threadIdx.x;
    int stride = gridDim.x * blockDim.x;
    for (int i = tid; i < n4; i += stride) {
        float4 v = x4[i];
        ushort4 h;
        h.x = f2bf(v.x); h.y = f2bf(v.y); h.z = f2bf(v.z); h.w = f2bf(v.w);
        xh4[i] = h;
    }
    for (int e = tid; e < E; e += stride) atomicAdd(&cnt[dst[e]], 1);
    if (tid < 4096) {
        int m = tid >> 11;
        int r = tid & 2047;
        int lane = r & 63;
        int nf = (r >> 6) & 7;
        int ks = r >> 9;
        const float* W = m ? W2 : W1;
        ushort* o = wp + m * 16384;
        int k0 = ks * 32 + ((lane >> 4) << 3);
        int c = nf * 16 + (lane & 15);
        #pragma unroll
        for (int i = 0; i < 8; ++i) o[r * 8 + i] = f2bf(W[(k0 + i) * D + c]);
    }
}

// ---------------- CSR alloc + fill ----------------
__global__ void alloc_kernel(const int* __restrict__ cnt, int* __restrict__ start,
                             int* __restrict__ cur, int* __restrict__ total, int n) {
    int i = blockIdx.x * blockDim.x + threadIdx.x;
    int lane = threadIdx.x & 63;
    int c = (i < n) ? cnt[i] : 0;
    int inc = c;
    #pragma unroll
    for (int s = 1; s < 64; s <<= 1) {
        int u = __shfl_up(inc, (unsigned)s);
        if (lane >= s) inc += u;
    }
    int base = 0;
    if (lane == 63) base = atomicAdd(total, inc);
    base = __shfl(base, 63);
    if (i < n) { int st = base + inc - c; start[i] = st; cur[i] = st; }
}

__global__ void fill_kernel(const int* __restrict__ src, const int* __restrict__ dst,
                            int* __restrict__ cur, int* __restrict__ bucket, int E) {
    int e = blockIdx.x * blockDim.x + threadIdx.x;
    if (e < E) {
        int p = atomicAdd(&cur[dst[e]], 1);
        bucket[p] = src[e];
    }
}

// ---------------- gather: z = xh + segment_sum(xh[src]) -> bf16 ----------------
__global__ void gather_kernel(const u16x8* __restrict__ xh8,
                              const int* __restrict__ start, const int* __restrict__ cnt,
                              const int* __restrict__ bucket,
                              u16x8* __restrict__ z8, int n) {
    int node = blockIdx.x * 16 + (threadIdx.x >> 4);
    int lane = threadIdx.x & 15;
    if (node >= n) return;
    int e0 = start[node];
    int eend = e0 + cnt[node];
    float a[8];
    #pragma unroll
    for (int j = 0; j < 8; ++j) a[j] = 0.f;
    int e = e0;
    for (; e + 8 <= eend; e += 8) {
        int s0 = bucket[e],     s1 = bucket[e + 1], s2 = bucket[e + 2], s3 = bucket[e + 3];
        int s4 = bucket[e + 4], s5 = bucket[e + 5], s6 = bucket[e + 6], s7 = bucket[e + 7];
        u16x8 v0 = xh8[(size_t)s0 * 16 + lane];
        u16x8 v1 = xh8[(size_t)s1 * 16 + lane];
        u16x8 v2 = xh8[(size_t)s2 * 16 + lane];
        u16x8 v3 = xh8[(size_t)s3 * 16 + lane];
        u16x8 v4 = xh8[(size_t)s4 * 16 + lane];
        u16x8 v5 = xh8[(size_t)s5 * 16 + lane];
        u16x8 v6 = xh8[(size_t)s6 * 16 + lane];
        u16x8 v7 = xh8[(size_t)s7 * 16 + lane];
        #pragma unroll
        for (int j = 0; j < 8; ++j) {
            a[j] += bf2f(v0[j]) + bf2f(v1[j]) + bf2f(v2[j]) + bf2f(v3[j])
                  + bf2f(v4[j]) + bf2f(v5[j]) + bf2f(v6[j]) + bf2f(v7[j]);
        }
    }
    for (; e + 4 <= eend; e += 4) {
        int s0 = bucket[e], s1 = bucket[e + 1], s2 = bucket[e + 2], s3 = bucket[e + 3];
        u16x8 v0 = xh8[(size_t)s0 * 16 + lane];
        u16x8 v1 = xh8[(size_t)s1 * 16 + lane];
        u16x8 v2 = xh8[(size_t)s2 * 16 + lane];
        u16x8 v3 = xh8[(size_t)s3 * 16 + lane];
        #pragma unroll
        for (int j = 0; j < 8; ++j)
            a[j] += bf2f(v0[j]) + bf2f(v1[j]) + bf2f(v2[j]) + bf2f(v3[j]);
    }
    for (; e < eend; ++e) {
        int s = bucket[e];
        u16x8 v = xh8[(size_t)s * 16 + lane];
        #pragma unroll
        for (int j = 0; j < 8; ++j) a[j] += bf2f(v[j]);
    }
    u16x8 xv = xh8[(size_t)node * 16 + lane];
    u16x8 zo;
    #pragma unroll
    for (int j = 0; j < 8; ++j) zo[j] = f2bf(a[j] + bf2f(xv[j]));
    z8[(size_t)node * 16 + lane] = zo;
}

// ---------------- GEMM1: h1 = relu(z @ W1 + b1), bf16 out ----------------
// Reg-W nf-split (R10) + 4-tile batch per wave: 16 A-loads issued before any
// MFMA -> 4x in-flight bytes (Little's law fix for the 0.8 TB/s starvation).
__global__ __launch_bounds__(256, 3)
void gemm1_kernel(const ushort* __restrict__ Z, const ushort* __restrict__ wp,
                  const float* __restrict__ bias, ushort* __restrict__ H1, int nTiles) {
    int wave = threadIdx.x >> 6, lane = threadIdx.x & 63;
    int rsel = lane & 15;
    int csel = lane >> 4;
    int nf0 = wave * 2;
    s16x8 w0[4], w1[4];
    #pragma unroll
    for (int ks = 0; ks < 4; ++ks) {
        w0[ks] = *(const s16x8*)(wp + ((ks * 8 + nf0) * 64 + lane) * 8);
        w1[ks] = *(const s16x8*)(wp + ((ks * 8 + nf0 + 1) * 64 + lane) * 8);
    }
    float bb0 = bias[nf0 * 16 + rsel];
    float bb1 = bias[(nf0 + 1) * 16 + rsel];
    for (int t0 = blockIdx.x * 4; t0 < nTiles; t0 += gridDim.x * 4) {
        int tn = nTiles - t0; if (tn > 4) tn = 4;
        s16x8 a[4][4];
        #pragma unroll
        for (int t = 0; t < 4; ++t) {
            if (t < tn) {
                const ushort* aP = Z + ((size_t)(t0 + t) * 16 + rsel) * D + csel * 8;
                a[t][0] = *(const s16x8*)(aP);
                a[t][1] = *(const s16x8*)(aP + 32);
                a[t][2] = *(const s16x8*)(aP + 64);
                a[t][3] = *(const s16x8*)(aP + 96);
            }
        }
        #pragma unroll
        for (int t = 0; t < 4; ++t) {
            if (t < tn) {
                f32x4 acc0 = (f32x4){0.f, 0.f, 0.f, 0.f};
                f32x4 acc1 = (f32x4){0.f, 0.f, 0.f, 0.f};
                #pragma unroll
                for (int ks = 0; ks < 4; ++ks) {
                    acc0 = __builtin_amdgcn_mfma_f32_16x16x32_bf16(a[t][ks], w0[ks], acc0, 0, 0, 0);
                    acc1 = __builtin_amdgcn_mfma_f32_16x16x32_bf16(a[t][ks], w1[ks], acc1, 0, 0, 0);
                }
                int col0 = nf0 * 16 + rsel;
                int orow = (t0 + t) * 16 + csel * 4;
                #pragma unroll
                for (int r = 0; r < 4; ++r) {
                    H1[(size_t)(orow + r) * D + col0]      = f2bf(fmaxf(acc0[r] + bb0, 0.f));
                    H1[(size_t)(orow + r) * D + col0 + 16] = f2bf(fmaxf(acc1[r] + bb1, 0.f));
                }
            }
        }
    }
}

// ---------------- GEMM2: out = h1 @ W2 + b2 (fp32) + BN stats ----------------
// Same 4-tile batch; stats in registers, one flush per wave.
__global__ __launch_bounds__(256, 3)
void gemm2_kernel(const ushort* __restrict__ H1, const ushort* __restrict__ wp,
                  const float* __restrict__ bias, float* __restrict__ out,
                  float* __restrict__ stats, int nTiles) {
    int wave = threadIdx.x >> 6, lane = threadIdx.x & 63;
    int rsel = lane & 15;
    int csel = lane >> 4;
    int nf0 = wave * 2;
    s16x8 w0[4], w1[4];
    #pragma unroll
    for (int ks = 0; ks < 4; ++ks) {
        w0[ks] = *(const s16x8*)(wp + ((ks * 8 + nf0) * 64 + lane) * 8);
        w1[ks] = *(const s16x8*)(wp + ((ks * 8 + nf0 + 1) * 64 + lane) * 8);
    }
    float bb0 = bias[nf0 * 16 + rsel];
    float bb1 = bias[(nf0 + 1) * 16 + rsel];
    float s0 = 0.f, q0 = 0.f, s1 = 0.f, q1 = 0.f;
    for (int t0 = blockIdx.x * 4; t0 < nTiles; t0 += gridDim.x * 4) {
        int tn = nTiles - t0; if (tn > 4) tn = 4;
        s16x8 a[4][4];
        #pragma unroll
        for (int t = 0; t < 4; ++t) {
            if (t < tn) {
                const ushort* aP = H1 + ((size_t)(t0 + t) * 16 + rsel) * D + csel * 8;
                a[t][0] = *(const s16x8*)(aP);
                a[t][1] = *(const s16x8*)(aP + 32);
                a[t][2] = *(const s16x8*)(aP + 64);
                a[t][3] = *(const s16x8*)(aP + 96);
            }
        }
        #pragma unroll
        for (int t = 0; t < 4; ++t) {
            if (t < tn) {
                f32x4 acc0 = (f32x4){0.f, 0.f, 0.f, 0.f};
                f32x4 acc1 = (f32x4){0.f, 0.f, 0.f, 0.f};
                #pragma unroll
                for (int ks = 0; ks < 4; ++ks) {
                    acc0 = __builtin_amdgcn_mfma_f32_16x16x32_bf16(a[t][ks], w0[ks], acc0, 0, 0, 0);
                    acc1 = __builtin_amdgcn_mfma_f32_16x16x32_bf16(a[t][ks], w1[ks], acc1, 0, 0, 0);
                }
                int col0 = nf0 * 16 + rsel;
                int orow = (t0 + t) * 16 + csel * 4;
                #pragma unroll
                for (int r = 0; r < 4; ++r) {
                    float v0 = acc0[r] + bb0;
                    float v1 = acc1[r] + bb1;
                    out[(size_t)(orow + r) * D + col0]      = v0;
                    out[(size_t)(orow + r) * D + col0 + 16] = v1;
                    s0 += v0; q0 += v0 * v0;
                    s1 += v1; q1 += v1 * v1;
                }
            }
        }
    }
    s0 += __shfl_xor(s0, 16); s0 += __shfl_xor(s0, 32);
    q0 += __shfl_xor(q0, 16); q0 += __shfl_xor(q0, 32);
    s1 += __shfl_xor(s1, 16); s1 += __shfl_xor(s1, 32);
    q1 += __shfl_xor(q1, 16); q1 += __shfl_xor(q1, 32);
    if (csel == 0) {
        int col0 = nf0 * 16 + rsel;
        atomicAdd(&stats[col0], s0);
        atomicAdd(&stats[128 + col0], q0);
        atomicAdd(&stats[col0 + 16], s1);
        atomicAdd(&stats[128 + col0 + 16], q1);
    }
}

// ---------------- BN normalize + residual ----------------
__global__ void bn_final(float4* __restrict__ out4, const float4* __restrict__ x4,
                         const float* __restrict__ stats, const float* __restrict__ gamma,
                         const float* __restrict__ beta, int n4, float invN) {
    int i = blockIdx.x * blockDim.x + threadIdx.x;
    if (i >= n4) return;
    int cc = i & 31;
    const float4* s4 = (const float4*)stats;
    float4 sum = s4[cc], sq = s4[32 + cc];
    float4 g = ((const float4*)gamma)[cc], b = ((const float4*)beta)[cc];
    float4 h = out4[i], xx = x4[i];
    float4 o;
    {
        float m = sum.x * invN, v = sq.x * invN - m * m, iv = rsqrtf(v + 1e-5f);
        o.x = (h.x - m) * iv * g.x + b.x + xx.x;
    }
    {
        float m = sum.y * invN, v = sq.y * invN - m * m, iv = rsqrtf(v + 1e-5f);
        o.y = (h.y - m) * iv * g.y + b.y + xx.y;
    }
    {
        float m = sum.z * invN, v = sq.z * invN - m * m, iv = rsqrtf(v + 1e-5f);
        o.z = (h.z - m) * iv * g.z + b.z + xx.z;
    }
    {
        float m = sum.w * invN, v = sq.w * invN - m * m, iv = rsqrtf(v + 1e-5f);
        o.w = (h.w - m) * iv * g.w + b.w + xx.w;
    }
    out4[i] = o;
}

extern "C" void kernel_launch(void* const* d_in, const int* in_sizes, int n_in,
                              void* d_out, int out_size, void* d_ws, size_t ws_size,
                              hipStream_t stream) {
    const float* x     = (const float*)d_in[0];
    const int*   ei    = (const int*)d_in[1];
    const float* W1    = (const float*)d_in[2];
    const float* b1    = (const float*)d_in[3];
    const float* W2    = (const float*)d_in[4];
    const float* b2    = (const float*)d_in[5];
    const float* gamma = (const float*)d_in[6];
    const float* beta  = (const float*)d_in[7];
    float* out = (float*)d_out;

    int N = in_sizes[0] / D;   // 50000
    int E = in_sizes[1] / 2;   // 600000
    const int* src = ei;
    const int* dst = ei + E;

    size_t NB = (size_t)N * D;
    ushort* xh   = (ushort*)d_ws;          // NB ushorts
    ushort* z    = xh + NB;                // NB ushorts
    ushort* h1   = z + NB;                 // NB ushorts
    ushort* wp   = h1 + NB;                // 2*16384
    float*  stats = (float*)(wp + 32768);  // 256 floats (16B aligned)
    int*    cnt  = (int*)(stats + 256);    // N
    int*    tot  = cnt + N;                // 1
    int*    startA = tot + 1;              // N
    int*    cur  = startA + N;             // N
    int*    bucket = cur + N;              // E

    hipMemsetAsync(stats, 0, (size_t)(256 + N + 1) * sizeof(int), stream);

    const int B = 256;
    int n4 = (int)(NB / 4);
    prep_kernel<<<2048, B, 0, stream>>>((const float4*)x, (ushort4*)xh, n4,
                                        dst, cnt, E, W1, W2, wp);
    alloc_kernel<<<(N + B - 1) / B, B, 0, stream>>>(cnt, startA, cur, tot, N);
    fill_kernel<<<(E + B - 1) / B, B, 0, stream>>>(src, dst, cur, bucket, E);
    gather_kernel<<<(N + 15) / 16, B, 0, stream>>>((const u16x8*)xh, startA, cnt, bucket,
                                                   (u16x8*)z, N);
    int nTiles = (N + 15) / 16;   // 3125
    gemm1_kernel<<<782, B, 0, stream>>>(z, wp, b1, h1, nTiles);
    gemm2_kernel<<<782, B, 0, stream>>>(h1, wp + 16384, b2, out, stats, nTiles);
    bn_final<<<(n4 + B - 1) / B, B, 0, stream>>>((float4*)out, (const float4*)x, stats,
                                                 gamma, beta, n4, 1.0f / (float)N);
}

// Round 12
// 154.444 us; speedup vs baseline: 1.3496x; 1.0882x over previous
//
#include <hip/hip_runtime.h>

#define D 128

typedef short s16x8 __attribute__((ext_vector_type(8)));
typedef ushort u16x8 __attribute__((ext_vector_type(8)));
typedef float f32x4 __attribute__((ext_vector_type(4)));

static __device__ __forceinline__ float bf2f(ushort h) {
    return __uint_as_float(((uint)h) << 16);
}
static __device__ __forceinline__ ushort f2bf(float f) {
    uint u = __float_as_uint(f);
    u += 0x7fffu + ((u >> 16) & 1u);   // RNE
    return (ushort)(u >> 16);
}

// ---------------- prep: x->bf16  +  degree count  +  W pack ----------------
__global__ void prep_kernel(const float4* __restrict__ x4, ushort4* __restrict__ xh4, int n4,
                            const int* __restrict__ dst, int* __restrict__ cnt, int E,
                            const float* __restrict__ W1, const float* __restrict__ W2,
                            ushort* __restrict__ wp) {
    int tid = blockIdx.x * blockDim.x + threadIdx.x;
    int stride = gridDim.x * blockDim.x;
    for (int i = tid; i < n4; i += stride) {
        float4 v = x4[i];
        ushort4 h;
        h.x = f2bf(v.x); h.y = f2bf(v.y); h.z = f2bf(v.z); h.w = f2bf(v.w);
        xh4[i] = h;
    }
    for (int e = tid; e < E; e += stride) atomicAdd(&cnt[dst[e]], 1);
    if (tid < 4096) {
        int m = tid >> 11;
        int r = tid & 2047;
        int lane = r & 63;
        int nf = (r >> 6) & 7;
        int ks = r >> 9;
        const float* W = m ? W2 : W1;
        ushort* o = wp + m * 16384;
        int k0 = ks * 32 + ((lane >> 4) << 3);
        int c = nf * 16 + (lane & 15);
        #pragma unroll
        for (int i = 0; i < 8; ++i) o[r * 8 + i] = f2bf(W[(k0 + i) * D + c]);
    }
}

// ---------------- CSR alloc + fill ----------------
__global__ void alloc_kernel(const int* __restrict__ cnt, int* __restrict__ start,
                             int* __restrict__ cur, int* __restrict__ total, int n) {
    int i = blockIdx.x * blockDim.x + threadIdx.x;
    int lane = threadIdx.x & 63;
    int c = (i < n) ? cnt[i] : 0;
    int inc = c;
    #pragma unroll
    for (int s = 1; s < 64; s <<= 1) {
        int u = __shfl_up(inc, (unsigned)s);
        if (lane >= s) inc += u;
    }
    int base = 0;
    if (lane == 63) base = atomicAdd(total, inc);
    base = __shfl(base, 63);
    if (i < n) { int st = base + inc - c; start[i] = st; cur[i] = st; }
}

__global__ void fill_kernel(const int* __restrict__ src, const int* __restrict__ dst,
                            int* __restrict__ cur, int* __restrict__ bucket, int E) {
    int e = blockIdx.x * blockDim.x + threadIdx.x;
    if (e < E) {
        int p = atomicAdd(&cur[dst[e]], 1);
        bucket[p] = src[e];
    }
}

// ---------------- gather: z = xh + segment_sum(xh[src]) -> bf16 ----------------
__global__ void gather_kernel(const u16x8* __restrict__ xh8,
                              const int* __restrict__ start, const int* __restrict__ cnt,
                              const int* __restrict__ bucket,
                              u16x8* __restrict__ z8, int n) {
    int node = blockIdx.x * 16 + (threadIdx.x >> 4);
    int lane = threadIdx.x & 15;
    if (node >= n) return;
    int e0 = start[node];
    int eend = e0 + cnt[node];
    float a[8];
    #pragma unroll
    for (int j = 0; j < 8; ++j) a[j] = 0.f;
    int e = e0;
    for (; e + 8 <= eend; e += 8) {
        int s0 = bucket[e],     s1 = bucket[e + 1], s2 = bucket[e + 2], s3 = bucket[e + 3];
        int s4 = bucket[e + 4], s5 = bucket[e + 5], s6 = bucket[e + 6], s7 = bucket[e + 7];
        u16x8 v0 = xh8[(size_t)s0 * 16 + lane];
        u16x8 v1 = xh8[(size_t)s1 * 16 + lane];
        u16x8 v2 = xh8[(size_t)s2 * 16 + lane];
        u16x8 v3 = xh8[(size_t)s3 * 16 + lane];
        u16x8 v4 = xh8[(size_t)s4 * 16 + lane];
        u16x8 v5 = xh8[(size_t)s5 * 16 + lane];
        u16x8 v6 = xh8[(size_t)s6 * 16 + lane];
        u16x8 v7 = xh8[(size_t)s7 * 16 + lane];
        #pragma unroll
        for (int j = 0; j < 8; ++j) {
            a[j] += bf2f(v0[j]) + bf2f(v1[j]) + bf2f(v2[j]) + bf2f(v3[j])
                  + bf2f(v4[j]) + bf2f(v5[j]) + bf2f(v6[j]) + bf2f(v7[j]);
        }
    }
    for (; e + 4 <= eend; e += 4) {
        int s0 = bucket[e], s1 = bucket[e + 1], s2 = bucket[e + 2], s3 = bucket[e + 3];
        u16x8 v0 = xh8[(size_t)s0 * 16 + lane];
        u16x8 v1 = xh8[(size_t)s1 * 16 + lane];
        u16x8 v2 = xh8[(size_t)s2 * 16 + lane];
        u16x8 v3 = xh8[(size_t)s3 * 16 + lane];
        #pragma unroll
        for (int j = 0; j < 8; ++j)
            a[j] += bf2f(v0[j]) + bf2f(v1[j]) + bf2f(v2[j]) + bf2f(v3[j]);
    }
    for (; e < eend; ++e) {
        int s = bucket[e];
        u16x8 v = xh8[(size_t)s * 16 + lane];
        #pragma unroll
        for (int j = 0; j < 8; ++j) a[j] += bf2f(v[j]);
    }
    u16x8 xv = xh8[(size_t)node * 16 + lane];
    u16x8 zo;
    #pragma unroll
    for (int j = 0; j < 8; ++j) zo[j] = f2bf(a[j] + bf2f(xv[j]));
    z8[(size_t)node * 16 + lane] = zo;
}

// ---------------- fused MLP: out = relu(z@W1+b1)@W2 + b2 (fp32) + BN stats ----------------
// Block = 4 waves = 4 tiles/iter. Reg-W for BOTH layers (64 VGPR), h1 lives only
// in 16KB of XOR-swizzled LDS (pattern validated R4/R5). One barrier per phase.
// nf-split: wave w owns output cols [w*32, w*32+32) in both layers.
__global__ __launch_bounds__(256, 3)
void fused_mlp(const ushort* __restrict__ Z, const ushort* __restrict__ wp,
               const float* __restrict__ b1, const float* __restrict__ b2,
               float* __restrict__ out, float* __restrict__ stats, int nTiles) {
    __shared__ ushort h1s[4][2048];   // 4 tiles x (16 rows x 128 cols bf16)
    int wave = threadIdx.x >> 6, lane = threadIdx.x & 63;
    int rsel = lane & 15;
    int csel = lane >> 4;
    int nf0 = wave * 2;
    const ushort* w1p = wp;
    const ushort* w2p = wp + 16384;
    s16x8 w10[4], w11[4], w20[4], w21[4];
    #pragma unroll
    for (int ks = 0; ks < 4; ++ks) {
        w10[ks] = *(const s16x8*)(w1p + ((ks * 8 + nf0) * 64 + lane) * 8);
        w11[ks] = *(const s16x8*)(w1p + ((ks * 8 + nf0 + 1) * 64 + lane) * 8);
        w20[ks] = *(const s16x8*)(w2p + ((ks * 8 + nf0) * 64 + lane) * 8);
        w21[ks] = *(const s16x8*)(w2p + ((ks * 8 + nf0 + 1) * 64 + lane) * 8);
    }
    float b10 = b1[nf0 * 16 + rsel], b11 = b1[(nf0 + 1) * 16 + rsel];
    float b20 = b2[nf0 * 16 + rsel], b21 = b2[(nf0 + 1) * 16 + rsel];
    float s0 = 0.f, q0 = 0.f, s1 = 0.f, q1 = 0.f;
    int col0 = nf0 * 16 + rsel;

    for (int t0 = blockIdx.x * 4; t0 < nTiles; t0 += gridDim.x * 4) {
        __syncthreads();   // LDS free from previous iteration
        // ---- phase 1: h1 tiles -> LDS (each wave: its 32 cols of all 4 tiles) ----
        #pragma unroll
        for (int t = 0; t < 4; ++t) {
            int tile = t0 + t;
            if (tile < nTiles) {
                const ushort* aP = Z + ((size_t)tile * 16 + rsel) * D + csel * 8;
                s16x8 a0 = *(const s16x8*)(aP);
                s16x8 a1 = *(const s16x8*)(aP + 32);
                s16x8 a2 = *(const s16x8*)(aP + 64);
                s16x8 a3 = *(const s16x8*)(aP + 96);
                f32x4 acc0 = (f32x4){0.f, 0.f, 0.f, 0.f};
                f32x4 acc1 = (f32x4){0.f, 0.f, 0.f, 0.f};
                acc0 = __builtin_amdgcn_mfma_f32_16x16x32_bf16(a0, w10[0], acc0, 0, 0, 0);
                acc1 = __builtin_amdgcn_mfma_f32_16x16x32_bf16(a0, w11[0], acc1, 0, 0, 0);
                acc0 = __builtin_amdgcn_mfma_f32_16x16x32_bf16(a1, w10[1], acc0, 0, 0, 0);
                acc1 = __builtin_amdgcn_mfma_f32_16x16x32_bf16(a1, w11[1], acc1, 0, 0, 0);
                acc0 = __builtin_amdgcn_mfma_f32_16x16x32_bf16(a2, w10[2], acc0, 0, 0, 0);
                acc1 = __builtin_amdgcn_mfma_f32_16x16x32_bf16(a2, w11[2], acc1, 0, 0, 0);
                acc0 = __builtin_amdgcn_mfma_f32_16x16x32_bf16(a3, w10[3], acc0, 0, 0, 0);
                acc1 = __builtin_amdgcn_mfma_f32_16x16x32_bf16(a3, w11[3], acc1, 0, 0, 0);
                char* tb = (char*)h1s[t];
                int c20 = col0 * 2, c21 = (col0 + 16) * 2;
                #pragma unroll
                for (int r = 0; r < 4; ++r) {
                    int rr = csel * 4 + r;
                    int sw = (rr & 7) << 4;
                    *(ushort*)(tb + rr * 256 + (c20 ^ sw)) = f2bf(fmaxf(acc0[r] + b10, 0.f));
                    *(ushort*)(tb + rr * 256 + (c21 ^ sw)) = f2bf(fmaxf(acc1[r] + b11, 0.f));
                }
            }
        }
        __syncthreads();
        // ---- phase 2: gemm2 from LDS h1 ----
        #pragma unroll
        for (int t = 0; t < 4; ++t) {
            int tile = t0 + t;
            if (tile < nTiles) {
                const char* tb = (const char*)h1s[t];
                int sw = (rsel & 7) << 4;
                s16x8 a0 = *(const s16x8*)(tb + rsel * 256 + ((csel * 16) ^ sw));
                s16x8 a1 = *(const s16x8*)(tb + rsel * 256 + ((64 + csel * 16) ^ sw));
                s16x8 a2 = *(const s16x8*)(tb + rsel * 256 + ((128 + csel * 16) ^ sw));
                s16x8 a3 = *(const s16x8*)(tb + rsel * 256 + ((192 + csel * 16) ^ sw));
                f32x4 acc0 = (f32x4){0.f, 0.f, 0.f, 0.f};
                f32x4 acc1 = (f32x4){0.f, 0.f, 0.f, 0.f};
                acc0 = __builtin_amdgcn_mfma_f32_16x16x32_bf16(a0, w20[0], acc0, 0, 0, 0);
                acc1 = __builtin_amdgcn_mfma_f32_16x16x32_bf16(a0, w21[0], acc1, 0, 0, 0);
                acc0 = __builtin_amdgcn_mfma_f32_16x16x32_bf16(a1, w20[1], acc0, 0, 0, 0);
                acc1 = __builtin_amdgcn_mfma_f32_16x16x32_bf16(a1, w21[1], acc1, 0, 0, 0);
                acc0 = __builtin_amdgcn_mfma_f32_16x16x32_bf16(a2, w20[2], acc0, 0, 0, 0);
                acc1 = __builtin_amdgcn_mfma_f32_16x16x32_bf16(a2, w21[2], acc1, 0, 0, 0);
                acc0 = __builtin_amdgcn_mfma_f32_16x16x32_bf16(a3, w20[3], acc0, 0, 0, 0);
                acc1 = __builtin_amdgcn_mfma_f32_16x16x32_bf16(a3, w21[3], acc1, 0, 0, 0);
                int orow = tile * 16 + csel * 4;
                #pragma unroll
                for (int r = 0; r < 4; ++r) {
                    float v0 = acc0[r] + b20;
                    float v1 = acc1[r] + b21;
                    out[(size_t)(orow + r) * D + col0]      = v0;
                    out[(size_t)(orow + r) * D + col0 + 16] = v1;
                    s0 += v0; q0 += v0 * v0;
                    s1 += v1; q1 += v1 * v1;
                }
            }
        }
    }
    // ---- flush stats ----
    s0 += __shfl_xor(s0, 16); s0 += __shfl_xor(s0, 32);
    q0 += __shfl_xor(q0, 16); q0 += __shfl_xor(q0, 32);
    s1 += __shfl_xor(s1, 16); s1 += __shfl_xor(s1, 32);
    q1 += __shfl_xor(q1, 16); q1 += __shfl_xor(q1, 32);
    if (csel == 0) {
        atomicAdd(&stats[col0], s0);
        atomicAdd(&stats[128 + col0], q0);
        atomicAdd(&stats[col0 + 16], s1);
        atomicAdd(&stats[128 + col0 + 16], q1);
    }
}

// ---------------- BN normalize + residual ----------------
__global__ void bn_final(float4* __restrict__ out4, const float4* __restrict__ x4,
                         const float* __restrict__ stats, const float* __restrict__ gamma,
                         const float* __restrict__ beta, int n4, float invN) {
    int i = blockIdx.x * blockDim.x + threadIdx.x;
    if (i >= n4) return;
    int cc = i & 31;
    const float4* s4 = (const float4*)stats;
    float4 sum = s4[cc], sq = s4[32 + cc];
    float4 g = ((const float4*)gamma)[cc], b = ((const float4*)beta)[cc];
    float4 h = out4[i], xx = x4[i];
    float4 o;
    {
        float m = sum.x * invN, v = sq.x * invN - m * m, iv = rsqrtf(v + 1e-5f);
        o.x = (h.x - m) * iv * g.x + b.x + xx.x;
    }
    {
        float m = sum.y * invN, v = sq.y * invN - m * m, iv = rsqrtf(v + 1e-5f);
        o.y = (h.y - m) * iv * g.y + b.y + xx.y;
    }
    {
        float m = sum.z * invN, v = sq.z * invN - m * m, iv = rsqrtf(v + 1e-5f);
        o.z = (h.z - m) * iv * g.z + b.z + xx.z;
    }
    {
        float m = sum.w * invN, v = sq.w * invN - m * m, iv = rsqrtf(v + 1e-5f);
        o.w = (h.w - m) * iv * g.w + b.w + xx.w;
    }
    out4[i] = o;
}

extern "C" void kernel_launch(void* const* d_in, const int* in_sizes, int n_in,
                              void* d_out, int out_size, void* d_ws, size_t ws_size,
                              hipStream_t stream) {
    const float* x     = (const float*)d_in[0];
    const int*   ei    = (const int*)d_in[1];
    const float* W1    = (const float*)d_in[2];
    const float* b1    = (const float*)d_in[3];
    const float* W2    = (const float*)d_in[4];
    const float* b2    = (const float*)d_in[5];
    const float* gamma = (const float*)d_in[6];
    const float* beta  = (const float*)d_in[7];
    float* out = (float*)d_out;

    int N = in_sizes[0] / D;   // 50000
    int E = in_sizes[1] / 2;   // 600000
    const int* src = ei;
    const int* dst = ei + E;

    size_t NB = (size_t)N * D;
    ushort* xh   = (ushort*)d_ws;          // NB ushorts
    ushort* z    = xh + NB;                // NB ushorts
    ushort* wp   = z + NB;                 // 2*16384
    float*  stats = (float*)(wp + 32768);  // 256 floats (16B aligned)
    int*    cnt  = (int*)(stats + 256);    // N
    int*    tot  = cnt + N;                // 1
    int*    startA = tot + 1;              // N
    int*    cur  = startA + N;             // N
    int*    bucket = cur + N;              // E

    hipMemsetAsync(stats, 0, (size_t)(256 + N + 1) * sizeof(int), stream);

    const int B = 256;
    int n4 = (int)(NB / 4);
    prep_kernel<<<2048, B, 0, stream>>>((const float4*)x, (ushort4*)xh, n4,
                                        dst, cnt, E, W1, W2, wp);
    alloc_kernel<<<(N + B - 1) / B, B, 0, stream>>>(cnt, startA, cur, tot, N);
    fill_kernel<<<(E + B - 1) / B, B, 0, stream>>>(src, dst, cur, bucket, E);
    gather_kernel<<<(N + 15) / 16, B, 0, stream>>>((const u16x8*)xh, startA, cnt, bucket,
                                                   (u16x8*)z, N);
    int nTiles = (N + 15) / 16;   // 3125
    fused_mlp<<<782, B, 0, stream>>>(z, wp, b1, b2, out, stats, nTiles);
    bn_final<<<(n4 + B - 1) / B, B, 0, stream>>>((float4*)out, (const float4*)x, stats,
                                                 gamma, beta, n4, 1.0f / (float)N);
}